// Round 2
// baseline (248.956 us; speedup 1.0000x reference)
//
#include <hip/hip_runtime.h>

#define NDIM 32
#define SCAN_BLOCK 256
#define SCAN_ELEMS 1024   // elements per scan block (256 threads x 4)

// ---------------- CSR build: histogram ----------------
__global__ void k_hist(const int* __restrict__ rows, int* __restrict__ cnt, int n_edges) {
    int e = blockIdx.x * blockDim.x + threadIdx.x;
    if (e < n_edges) atomicAdd(&cnt[rows[e]], 1);
}

// ---------------- exclusive scan (3 kernels) ----------------
__global__ void k_scan1(int* __restrict__ cnt, int* __restrict__ partials, int n) {
    __shared__ int lds[SCAN_BLOCK];
    int t = threadIdx.x;
    int base = blockIdx.x * SCAN_ELEMS + t * 4;
    int v0 = 0, v1 = 0, v2 = 0, v3 = 0;
    if (base + 0 < n) v0 = cnt[base + 0];
    if (base + 1 < n) v1 = cnt[base + 1];
    if (base + 2 < n) v2 = cnt[base + 2];
    if (base + 3 < n) v3 = cnt[base + 3];
    int s = v0 + v1 + v2 + v3;
    lds[t] = s;
    __syncthreads();
    for (int off = 1; off < SCAN_BLOCK; off <<= 1) {
        int x = 0;
        if (t >= off) x = lds[t - off];
        __syncthreads();
        if (t >= off) lds[t] += x;
        __syncthreads();
    }
    int excl = lds[t] - s;              // exclusive prefix within block
    if (t == SCAN_BLOCK - 1) partials[blockIdx.x] = lds[t];  // block total
    if (base + 0 < n) cnt[base + 0] = excl;  excl += v0;
    if (base + 1 < n) cnt[base + 1] = excl;  excl += v1;
    if (base + 2 < n) cnt[base + 2] = excl;  excl += v2;
    if (base + 3 < n) cnt[base + 3] = excl;
}

__global__ void k_scan2(int* __restrict__ partials, int p) {
    __shared__ int lds[128];
    int t = threadIdx.x;
    int v = (t < p) ? partials[t] : 0;
    lds[t] = v;
    __syncthreads();
    for (int off = 1; off < 128; off <<= 1) {
        int x = 0;
        if (t >= off) x = lds[t - off];
        __syncthreads();
        if (t >= off) lds[t] += x;
        __syncthreads();
    }
    if (t < p) partials[t] = lds[t] - v;   // exclusive scan of block totals
}

__global__ void k_scan3(int* __restrict__ cnt, const int* __restrict__ partials, int n) {
    int add = partials[blockIdx.x];
    int base = blockIdx.x * SCAN_ELEMS + threadIdx.x * 4;
    if (base + 0 < n) cnt[base + 0] += add;
    if (base + 1 < n) cnt[base + 1] += add;
    if (base + 2 < n) cnt[base + 2] += add;
    if (base + 3 < n) cnt[base + 3] += add;
}

// ---------------- scatter edges into CSR order ----------------
__global__ void k_scatter(const int* __restrict__ rows, const int* __restrict__ cols,
                          const float* __restrict__ vals,
                          int* __restrict__ cnt, int2* __restrict__ edges, int n_edges) {
    int e = blockIdx.x * blockDim.x + threadIdx.x;
    if (e >= n_edges) return;
    int r = rows[e];
    int pos = atomicAdd(&cnt[r], 1);   // cnt[r] ends at end(r) = start(r+1)
    int2 cv;
    cv.x = cols[e];
    cv.y = __float_as_int(vals[e]);
    edges[pos] = cv;
}

// ---------------- gather: one 32-lane group per row, no atomics ----------------
__global__ void k_gather(const int* __restrict__ cnt, const int2* __restrict__ edges,
                         const float* __restrict__ feat, float* __restrict__ out,
                         int n_nodes) {
    int g = blockIdx.x * blockDim.x + threadIdx.x;
    int row = g >> 5;
    int d = g & 31;
    if (row >= n_nodes) return;
    // after scatter: cnt[r] == end(r); start(r) == cnt[r-1], start(0) == 0
    int end = cnt[row];
    int start = (row == 0) ? 0 : cnt[row - 1];
    float acc = 0.f;
    int j = start;
    for (; j + 1 < end; j += 2) {      // 2x unroll for ILP on the gather chain
        int2 a = edges[j];
        int2 b = edges[j + 1];
        acc += __int_as_float(a.y) * feat[(long long)a.x * NDIM + d];
        acc += __int_as_float(b.y) * feat[(long long)b.x * NDIM + d];
    }
    if (j < end) {
        int2 a = edges[j];
        acc += __int_as_float(a.y) * feat[(long long)a.x * NDIM + d];
    }
    out[(long long)row * NDIM + d] = acc;
}

// ---------------- fallback (round-1): direct atomic scatter ----------------
__global__ void gc_scatter_atomic(const int* __restrict__ rows, const int* __restrict__ cols,
                                  const float* __restrict__ vals, const float* __restrict__ feat,
                                  float* __restrict__ out, int n_edges) {
    long long gid = (long long)blockIdx.x * blockDim.x + threadIdx.x;
    int e = (int)(gid >> 5);
    int d = (int)(gid & 31);
    if (e >= n_edges) return;
    float f = feat[(long long)cols[e] * NDIM + d];
    atomicAdd(&out[(long long)rows[e] * NDIM + d], vals[e] * f);
}

static inline size_t align_up(size_t x, size_t a) { return (x + a - 1) & ~(a - 1); }

extern "C" void kernel_launch(void* const* d_in, const int* in_sizes, int n_in,
                              void* d_out, int out_size, void* d_ws, size_t ws_size,
                              hipStream_t stream) {
    const int*   rows = (const int*)d_in[0];
    const int*   cols = (const int*)d_in[1];
    const float* vals = (const float*)d_in[2];
    const float* feat = (const float*)d_in[3];
    float*       out  = (float*)d_out;

    const int n_edges = in_sizes[0];
    const int n_nodes = in_sizes[3] / NDIM;
    const int n_scan_blocks = (n_nodes + SCAN_ELEMS - 1) / SCAN_ELEMS;  // 98 for N=100000

    // workspace layout
    size_t cnt_bytes  = align_up((size_t)n_nodes * sizeof(int), 256);
    size_t part_bytes = align_up((size_t)n_scan_blocks * sizeof(int), 256);
    size_t edge_bytes = (size_t)n_edges * sizeof(int2);
    size_t need = cnt_bytes + part_bytes + edge_bytes;

    if (ws_size < need || n_scan_blocks > 128) {
        // fallback: direct atomic scatter (correct, slower)
        hipMemsetAsync(out, 0, (size_t)out_size * sizeof(float), stream);
        long long total = (long long)n_edges * NDIM;
        unsigned nblock = (unsigned)((total + 255) / 256);
        gc_scatter_atomic<<<nblock, 256, 0, stream>>>(rows, cols, vals, feat, out, n_edges);
        return;
    }

    char* w = (char*)d_ws;
    int*  cnt      = (int*)w;
    int*  partials = (int*)(w + cnt_bytes);
    int2* edges    = (int2*)(w + cnt_bytes + part_bytes);

    hipMemsetAsync(cnt, 0, (size_t)n_nodes * sizeof(int), stream);

    const int eb = (n_edges + 255) / 256;
    k_hist<<<eb, 256, 0, stream>>>(rows, cnt, n_edges);
    k_scan1<<<n_scan_blocks, SCAN_BLOCK, 0, stream>>>(cnt, partials, n_nodes);
    k_scan2<<<1, 128, 0, stream>>>(partials, n_scan_blocks);
    k_scan3<<<n_scan_blocks, SCAN_BLOCK, 0, stream>>>(cnt, partials, n_nodes);
    k_scatter<<<eb, 256, 0, stream>>>(rows, cols, vals, cnt, edges, n_edges);

    long long gthreads = (long long)n_nodes * NDIM;
    unsigned  gblocks  = (unsigned)((gthreads + 255) / 256);
    k_gather<<<gblocks, 256, 0, stream>>>(cnt, edges, feat, out, n_nodes);
}